// Round 12
// baseline (32.867 us; speedup 1.0000x reference)
//
#include <hip/hip_runtime.h>
#include <cstdint>

#define NPTS 512
#define DIM 256
#define NBLK 256
#define LDB 264                  // shorts per LDS row (528 B, padded)
#define MARGIN_F 0.2f
#define FIX_SCALE 1073741824.0   // 2^30
#define SUM_BITS 42
#define CNT_SHIFT 42
#define TAG_SHIFT 56
#define PART_TAG 0x55ull

typedef __attribute__((ext_vector_type(8))) short bf16x8;   // 8 bf16 = 4 VGPR
typedef __attribute__((ext_vector_type(4))) float f32x4;

__device__ __forceinline__ uint32_t rotl32(uint32_t x, uint32_t r) {
  return (x << r) | (x >> (32u - r));
}

__device__ __forceinline__ ushort f2bf(float f) {   // RNE float->bf16
  uint32_t u = __float_as_uint(f);
  return (ushort)((u + 0x7FFFu + ((u >> 16) & 1u)) >> 16);
}
__device__ __forceinline__ float bf2f(ushort h) {
  return __uint_as_float(((uint32_t)h) << 16);
}

// Split 8 floats into packed hi/lo bf16 uint4s.
__device__ __forceinline__ void split8(const float4 v0, const float4 v1,
                                       uint4& hi, uint4& lo) {
  const float f[8] = {v0.x, v0.y, v0.z, v0.w, v1.x, v1.y, v1.z, v1.w};
  uint32_t h[8], l[8];
  #pragma unroll
  for (int e = 0; e < 8; ++e) {
    const ushort hh = f2bf(f[e]);
    h[e] = hh;
    l[e] = f2bf(f[e] - bf2f(hh));
  }
  hi.x = h[0] | (h[1] << 16); hi.y = h[2] | (h[3] << 16);
  hi.z = h[4] | (h[5] << 16); hi.w = h[6] | (h[7] << 16);
  lo.x = l[0] | (l[1] << 16); lo.y = l[2] | (l[3] << 16);
  lo.z = l[4] | (l[5] << 16); lo.w = l[6] | (l[7] << 16);
}

// JAX threefry2x32, key (0, 42), partitionable mode: bits = out0 ^ out1,
// counter x = (hi32(m)=0, lo32(m)=m). Verified bit-exact (absmax 0.0, r1-r11).
__device__ __forceinline__ uint32_t threefry_bits(uint32_t c1) {
  const uint32_t k0 = 0u, k1 = 42u;
  const uint32_t k2 = k0 ^ k1 ^ 0x1BD11BDAu;
  uint32_t x0 = 0u + k0;
  uint32_t x1 = c1 + k1;
#define TFR(r) { x0 += x1; x1 = rotl32(x1, r); x1 ^= x0; }
  TFR(13u) TFR(15u) TFR(26u) TFR(6u)
  x0 += k1; x1 += k2 + 1u;
  TFR(17u) TFR(29u) TFR(16u) TFR(24u)
  x0 += k2; x1 += k0 + 2u;
  TFR(13u) TFR(15u) TFR(26u) TFR(6u)
  x0 += k0; x1 += k1 + 3u;
  TFR(17u) TFR(29u) TFR(16u) TFR(24u)
  x0 += k1; x1 += k2 + 4u;
  TFR(13u) TFR(15u) TFR(26u) TFR(6u)
  x0 += k2; x1 += k0 + 5u;
#undef TFR
  return x0 ^ x1;
}

// Single-dispatch fused kernel: block b owns anchors 2b, 2b+1 and has NO
// dependency on any other block (except the benign tagged part[] gather by
// block 0). Per block: stream all 512 emb rows through double-buffered
// bf16-split LDS tiles; MFMA (2 anchor rows in a 16-row A tile) builds the
// two sqd rows; then the verified semi-hard scan runs on LDS data.
__global__ __launch_bounds__(512) void triplet_one(
    const float* __restrict__ emb,
    const int* __restrict__ labels,
    unsigned long long* part,
    float* __restrict__ out)
{
  __shared__ __align__(16) ushort Ahi[16][LDB];
  __shared__ __align__(16) ushort Alo[16][LDB];
  __shared__ __align__(16) ushort Bhi[2][32][LDB];
  __shared__ __align__(16) ushort Blo[2][32][LDB];
  __shared__ float pG[2][8][2][16];   // [buf][wave][row0/1][col]
  __shared__ float snrm[NPTS];
  __shared__ float sd0[NPTS];
  __shared__ float sd1[NPTS];
  __shared__ int   slab[NPTS];
  __shared__ int   plist[256];
  __shared__ int   pcnt;
  __shared__ float sna0, sna1;
  __shared__ unsigned long long wsum[8], wcnt[8];

  const int b = blockIdx.x;
  const int t = threadIdx.x;
  const int wave = t >> 6;
  const int lane = t & 63;
  const int a0 = 2 * b;
  const int a1 = a0 + 1;

  // ---- stage one 32-row j-tile as bf16-split + fp32 row norms ----
  auto STAGE = [&](int jt, int buf) {
    #pragma unroll
    for (int it = 0; it < 2; ++it) {
      const int cidx = (it << 9) + t;      // 0..1023
      const int rr = cidx >> 5;            // row in tile 0..31
      const int c8 = cidx & 31;            // 8-float chunk
      const int gr = (jt << 5) + rr;       // global row
      const float* p = emb + gr * DIM + c8 * 8;
      const float4 v0 = *reinterpret_cast<const float4*>(p);
      const float4 v1 = *reinterpret_cast<const float4*>(p + 4);
      uint4 hi, lo;
      split8(v0, v1, hi, lo);
      *reinterpret_cast<uint4*>(&Bhi[buf][rr][c8 * 8]) = hi;
      *reinterpret_cast<uint4*>(&Blo[buf][rr][c8 * 8]) = lo;
      float q = v0.x * v0.x + v0.y * v0.y + v0.z * v0.z + v0.w * v0.w
              + v1.x * v1.x + v1.y * v1.y + v1.z * v1.z + v1.w * v1.w;
      #pragma unroll
      for (int m = 16; m; m >>= 1) q += __shfl_xor(q, m);   // 32-thread row group
      if ((t & 31) == 0) snrm[gr] = q;
    }
  };

  // ---- MFMA on the current tile: wave -> (subtile = w>>2, kquarter = w&3) --
  auto MFMA = [&](int buf) {
    const int sb = wave >> 2;
    const int frow = lane & 15;                 // A row (0..15; rows 0,1 live)
    const int fcol = (sb << 4) + (lane & 15);   // B row within tile
    const int kg = lane >> 4;
    f32x4 acc_h = {0.f, 0.f, 0.f, 0.f};
    f32x4 acc_hl = {0.f, 0.f, 0.f, 0.f};
    f32x4 acc_lh = {0.f, 0.f, 0.f, 0.f};
    #pragma unroll
    for (int s2 = 0; s2 < 2; ++s2) {
      const int kb = ((wave & 3) * 2 + s2) * 32 + kg * 8;
      const bf16x8 ah = *reinterpret_cast<const bf16x8*>(&Ahi[frow][kb]);
      const bf16x8 al = *reinterpret_cast<const bf16x8*>(&Alo[frow][kb]);
      const bf16x8 bh = *reinterpret_cast<const bf16x8*>(&Bhi[buf][fcol][kb]);
      const bf16x8 bl = *reinterpret_cast<const bf16x8*>(&Blo[buf][fcol][kb]);
      acc_h  = __builtin_amdgcn_mfma_f32_16x16x32_bf16(ah, bh, acc_h,  0, 0, 0);
      acc_hl = __builtin_amdgcn_mfma_f32_16x16x32_bf16(ah, bl, acc_hl, 0, 0, 0);
      acc_lh = __builtin_amdgcn_mfma_f32_16x16x32_bf16(al, bh, acc_lh, 0, 0, 0);
    }
    // C/D: col = lane&15, row = (lane>>4)*4 + j  -> rows 0,1 live in lanes 0-15
    if (lane < 16) {
      pG[buf][wave][0][lane] = (acc_h[0] + acc_hl[0]) + acc_lh[0];
      pG[buf][wave][1][lane] = (acc_h[1] + acc_hl[1]) + acc_lh[1];
    }
  };

  // ---- finalize tile jtf: sum 4 K-quarter partials, build sd rows ----
  auto FIN = [&](int jtf, int bf) {
    if (t < 64) {
      const int c = t & 31;         // col in tile
      const int which = t >> 5;     // 0 -> sd0, 1 -> sd1
      const int sb = c >> 4;
      const int cl = c & 15;
      const float g = ((pG[bf][sb * 4 + 0][which][cl] + pG[bf][sb * 4 + 1][which][cl])
                     + (pG[bf][sb * 4 + 2][which][cl] + pG[bf][sb * 4 + 3][which][cl]));
      const int j = (jtf << 5) + c;
      const float na = which ? sna1 : sna0;
      const float v = na + snrm[j] - 2.f * g;
      const float sdv = v > 0.f ? v : 0.f;
      if (which) sd1[j] = sdv; else sd0[j] = sdv;
    }
  };

  // ================= Prologue =================
  if (t == 0) pcnt = 0;
  slab[t] = labels[t];
  // zero A rows 2..15 (hi+lo): 2 x 14 x 33 uint4 = 924 tasks
  for (int u = t; u < 924; u += 512) {
    const int arr = (u >= 462);
    const int uu = arr ? u - 462 : u;
    const int rr = 2 + uu / 33;
    const int cc = uu % 33;
    uint4 z; z.x = 0; z.y = 0; z.z = 0; z.w = 0;
    if (arr) *reinterpret_cast<uint4*>(&Alo[rr][cc * 8]) = z;
    else     *reinterpret_cast<uint4*>(&Ahi[rr][cc * 8]) = z;
  }
  // stage anchor rows into A rows 0,1
  if (t < 64) {
    const int rr = t >> 5;
    const int c8 = t & 31;
    const float* p = emb + (a0 + rr) * DIM + c8 * 8;
    const float4 v0 = *reinterpret_cast<const float4*>(p);
    const float4 v1 = *reinterpret_cast<const float4*>(p + 4);
    uint4 hi, lo;
    split8(v0, v1, hi, lo);
    *reinterpret_cast<uint4*>(&Ahi[rr][c8 * 8]) = hi;
    *reinterpret_cast<uint4*>(&Alo[rr][c8 * 8]) = lo;
  }
  // anchor norms (fp32, wave-reduced)
  if (wave < 2) {
    const float4 v = *reinterpret_cast<const float4*>(emb + (a0 + wave) * DIM + lane * 4);
    float q = v.x * v.x + v.y * v.y + v.z * v.z + v.w * v.w;
    #pragma unroll
    for (int m = 32; m; m >>= 1) q += __shfl_xor(q, m);
    if (lane == 0) { if (wave) sna1 = q; else sna0 = q; }
  }
  STAGE(0, 0);
  __syncthreads();

  // positive-pair list (needs only slab)
  {
    const int lp = slab[t];
    if (t != a0 && lp == slab[a0]) { int k = atomicAdd(&pcnt, 1); plist[k] = t; }
    if (t != a1 && lp == slab[a1]) { int k = atomicAdd(&pcnt, 1); plist[k] = (1 << 16) | t; }
  }

  // ================= Main pipeline: 16 j-tiles =================
  for (int jt = 0; jt < 16; ++jt) {
    if (jt < 15) STAGE(jt + 1, (jt + 1) & 1);
    MFMA(jt & 1);
    if (jt > 0) FIN(jt - 1, (jt - 1) & 1);
    __syncthreads();
  }
  FIN(15, 1);
  __syncthreads();

  // ================= Semi-hard scan (r11-verified) =================
  float d0v[8], d1v[8];
  int labv[8];
  #pragma unroll
  for (int k = 0; k < 8; ++k) {
    const int j = lane + (k << 6);
    d0v[k] = sd0[j];
    d1v[k] = sd1[j];
    labv[k] = slab[j];
  }

  unsigned long long lsum = 0ull, lcnt = 0ull;
  const int np = pcnt;
  for (int e = wave; e < np; e += 8) {
    const int ent = plist[e];
    const int ai = ent >> 16;
    const int p = ent & 0xffff;
    const int ag = ai ? a1 : a0;
    const int la = slab[ag];
    const float dap = ai ? sd1[p] : sd0[p];
    const float hi = dap + MARGIN_F;
    const uint32_t base = ((uint32_t)ag << 18) | ((uint32_t)p << 9);

    int bestKey = -1, bestJ = 0;
    #pragma unroll
    for (int k = 0; k < 8; ++k) {
      const int j = lane + (k << 6);
      const float dj = ai ? d1v[k] : d0v[k];
      if (labv[k] != la && dj > dap && dj < hi) {
        const int key = (int)(threefry_bits(base + (uint32_t)j) >> 9);
        if (key > bestKey) { bestKey = key; bestJ = j; }
      }
    }
    #pragma unroll
    for (int m = 32; m; m >>= 1) {
      const int ok = __shfl_xor(bestKey, m);
      const int oj = __shfl_xor(bestJ, m);
      if (ok > bestKey || (ok == bestKey && oj < bestJ)) { bestKey = ok; bestJ = oj; }
    }
    if (lane == 0 && bestKey >= 0) {
      const float term = (dap - (ai ? sd1[bestJ] : sd0[bestJ])) + MARGIN_F;
      lsum += (unsigned long long)((double)term * FIX_SCALE + 0.5);
      lcnt += 1ull;
    }
  }

  if (lane == 0) { wsum[wave] = lsum; wcnt[wave] = lcnt; }
  __syncthreads();
  if (t == 0) {
    unsigned long long s = 0ull, c = 0ull;
    #pragma unroll
    for (int w = 0; w < 8; ++w) { s += wsum[w]; c += wcnt[w]; }
    const unsigned long long val = (PART_TAG << TAG_SHIFT) | (c << CNT_SHIFT) | s;
    __hip_atomic_store(&part[b], val, __ATOMIC_RELEASE, __HIP_MEMORY_SCOPE_AGENT);
  }

  // ---- block 0, wave 0: gather 256 tagged parts (replay-safe), finalize ----
  if (b == 0 && wave == 0) {
    unsigned long long s = 0ull, c = 0ull;
    #pragma unroll
    for (int k = 0; k < 4; ++k) {
      const int slot = lane * 4 + k;
      unsigned long long v;
      do {
        v = __hip_atomic_load(&part[slot], __ATOMIC_ACQUIRE,
                              __HIP_MEMORY_SCOPE_AGENT);
      } while ((v >> TAG_SHIFT) != PART_TAG);
      s += v & ((1ull << SUM_BITS) - 1ull);
      c += (v >> CNT_SHIFT) & 0x3FFFull;
    }
    #pragma unroll
    for (int m = 32; m; m >>= 1) {
      s += __shfl_xor(s, m);
      c += __shfl_xor(c, m);
    }
    if (lane == 0) {
      const double sd = (double)s / FIX_SCALE;
      const double cd = c ? (double)c : 1.0;
      out[0] = (float)(sd / cd);
    }
  }
}

extern "C" void kernel_launch(void* const* d_in, const int* in_sizes, int n_in,
                              void* d_out, int out_size, void* d_ws, size_t ws_size,
                              hipStream_t stream) {
  const float* emb  = (const float*)d_in[0];
  const int* labels = (const int*)d_in[1];
  float* out        = (float*)d_out;
  unsigned long long* part = (unsigned long long*)d_ws;   // 256 * 8 B, tag-gated

  triplet_one<<<dim3(NBLK), dim3(512), 0, stream>>>(emb, labels, part, out);
}

// Round 13
// 19.385 us; speedup vs baseline: 1.6954x; 1.6954x over previous
//
#include <hip/hip_runtime.h>
#include <cstdint>

#define NPTS 512
#define DIM 256
#define NBLK (NPTS / 2)
#define TK 32
#define LDB 264             // bf16 elements per LDS row (padded: 528 B/row, 16B-aligned)
#define MARGIN_F 0.2f
#define FIX_SCALE 1073741824.0   // 2^30
#define SUM_BITS 42
#define CNT_SHIFT 42
#define DONE_SHIFT 56

typedef __attribute__((ext_vector_type(8))) short bf16x8;   // 8 bf16 = 4 VGPR
typedef __attribute__((ext_vector_type(4))) float f32x4;

__device__ __forceinline__ uint32_t rotl32(uint32_t x, uint32_t r) {
  return (x << r) | (x >> (32u - r));
}

__device__ __forceinline__ ushort f2bf(float f) {   // RNE float->bf16
  uint32_t u = __float_as_uint(f);
  return (ushort)((u + 0x7FFFu + ((u >> 16) & 1u)) >> 16);
}
__device__ __forceinline__ float bf2f(ushort h) {
  return __uint_as_float(((uint32_t)h) << 16);
}

// Split 8 floats into packed hi/lo bf16 uint4s (RNE, lo = f - hi exactly).
__device__ __forceinline__ void split8(const float4 v0, const float4 v1,
                                       uint4& hi, uint4& lo) {
  const float f[8] = {v0.x, v0.y, v0.z, v0.w, v1.x, v1.y, v1.z, v1.w};
  uint32_t h[8], l[8];
  #pragma unroll
  for (int e = 0; e < 8; ++e) {
    const ushort hh = f2bf(f[e]);
    h[e] = hh;
    l[e] = f2bf(f[e] - bf2f(hh));
  }
  hi.x = h[0] | (h[1] << 16); hi.y = h[2] | (h[3] << 16);
  hi.z = h[4] | (h[5] << 16); hi.w = h[6] | (h[7] << 16);
  lo.x = l[0] | (l[1] << 16); lo.y = l[2] | (l[3] << 16);
  lo.z = l[4] | (l[5] << 16); lo.w = l[6] | (l[7] << 16);
}

// JAX threefry2x32, key (0, 42), partitionable mode: bits = out0 ^ out1,
// counter x = (hi32(m)=0, lo32(m)=m). Verified bit-exact (absmax 0.0, r1-r12).
__device__ __forceinline__ uint32_t threefry_bits(uint32_t c1) {
  const uint32_t k0 = 0u, k1 = 42u;
  const uint32_t k2 = k0 ^ k1 ^ 0x1BD11BDAu;
  uint32_t x0 = 0u + k0;
  uint32_t x1 = c1 + k1;
#define TFR(r) { x0 += x1; x1 = rotl32(x1, r); x1 ^= x0; }
  TFR(13u) TFR(15u) TFR(26u) TFR(6u)
  x0 += k1; x1 += k2 + 1u;
  TFR(17u) TFR(29u) TFR(16u) TFR(24u)
  x0 += k2; x1 += k0 + 2u;
  TFR(13u) TFR(15u) TFR(26u) TFR(6u)
  x0 += k0; x1 += k1 + 3u;
  TFR(17u) TFR(29u) TFR(16u) TFR(24u)
  x0 += k1; x1 += k2 + 4u;
  TFR(13u) TFR(15u) TFR(26u) TFR(6u)
  x0 += k2; x1 += k0 + 5u;
#undef TFR
  return x0 ^ x1;
}

// ---- K1: Gram via bf16-split MFMA. Block b -> 32x32 tile (b>>4, b&15). ----
// 256 threads = 4 waves = the 4 MFMA quadrants (no idle waves; halves the
// dispatch's wave count vs 512-thread version; 2 blocks/CU now fit in LDS).
__global__ __launch_bounds__(256) void gram_kernel(
    const float* __restrict__ emb,
    float* __restrict__ G,
    float* __restrict__ dg,
    unsigned long long* __restrict__ gsum)
{
  __shared__ __align__(16) ushort Ahi[TK][LDB];
  __shared__ __align__(16) ushort Alo[TK][LDB];
  __shared__ __align__(16) ushort Bhi[TK][LDB];
  __shared__ __align__(16) ushort Blo[TK][LDB];

  const int b = blockIdx.x;
  const int ti = b >> 4, tj = b & 15;
  const int t = threadIdx.x;
  const int wave = t >> 6;
  const int lane = t & 63;

  if (b == 0 && t == 0) *gsum = 0ull;   // replaces a memset dispatch

  // ---- stage + split-convert: 1024 8-float chunks / 256 threads = 4 each --
  #pragma unroll
  for (int it = 0; it < 4; ++it) {
    const int cidx = (it << 8) + t;     // 0..1023
    const int r = cidx >> 5;            // row 0..31
    const int c8 = cidx & 31;           // 8-float chunk within row
    const float* pa = emb + (ti * TK + r) * DIM + c8 * 8;
    const float4 a0 = *reinterpret_cast<const float4*>(pa);
    const float4 a1 = *reinterpret_cast<const float4*>(pa + 4);
    uint4 ahi, alo;
    split8(a0, a1, ahi, alo);
    *reinterpret_cast<uint4*>(&Ahi[r][c8 * 8]) = ahi;
    *reinterpret_cast<uint4*>(&Alo[r][c8 * 8]) = alo;
    uint4 bhi, blo;
    if (ti == tj) { bhi = ahi; blo = alo; }
    else {
      const float* pb = emb + (tj * TK + r) * DIM + c8 * 8;
      const float4 b0 = *reinterpret_cast<const float4*>(pb);
      const float4 b1 = *reinterpret_cast<const float4*>(pb + 4);
      split8(b0, b1, bhi, blo);
    }
    *reinterpret_cast<uint4*>(&Bhi[r][c8 * 8]) = bhi;
    *reinterpret_cast<uint4*>(&Blo[r][c8 * 8]) = blo;
  }
  __syncthreads();

  // ---- MFMA phase: wave -> quadrant (qr,qc) = (wave>>1, wave&1) ----
  {
    const int qr = wave >> 1, qc = wave & 1;
    const int frow = qr * 16 + (lane & 15);   // A-fragment row
    const int fcol = qc * 16 + (lane & 15);   // B-fragment col (B^T row)
    const int kg = lane >> 4;                 // k-group 0..3

    f32x4 acc_h  = {0.f, 0.f, 0.f, 0.f};
    f32x4 acc_hl = {0.f, 0.f, 0.f, 0.f};
    f32x4 acc_lh = {0.f, 0.f, 0.f, 0.f};
    #pragma unroll
    for (int s = 0; s < 8; ++s) {
      const int kb = s * 32 + kg * 8;
      const bf16x8 ah = *reinterpret_cast<const bf16x8*>(&Ahi[frow][kb]);
      const bf16x8 al = *reinterpret_cast<const bf16x8*>(&Alo[frow][kb]);
      const bf16x8 bh = *reinterpret_cast<const bf16x8*>(&Bhi[fcol][kb]);
      const bf16x8 bl = *reinterpret_cast<const bf16x8*>(&Blo[fcol][kb]);
      acc_h  = __builtin_amdgcn_mfma_f32_16x16x32_bf16(ah, bh, acc_h,  0, 0, 0);
      acc_hl = __builtin_amdgcn_mfma_f32_16x16x32_bf16(ah, bl, acc_hl, 0, 0, 0);
      acc_lh = __builtin_amdgcn_mfma_f32_16x16x32_bf16(al, bh, acc_lh, 0, 0, 0);
    }

    // C/D layout (m89): col = lane&15, row = (lane>>4)*4 + j
    const int lc = qc * 16 + (lane & 15);
    #pragma unroll
    for (int j = 0; j < 4; ++j) {
      const int lr = qr * 16 + (lane >> 4) * 4 + j;
      const float g = (acc_h[j] + acc_hl[j]) + acc_lh[j];
      G[(ti * TK + lr) * NPTS + (tj * TK + lc)] = g;
      if (ti == tj && lr == lc) dg[ti * TK + lr] = g;
    }
  }
}

// ---- K2: semi-hard scan. One block per 2 anchors, 256 threads = 4 waves. --
__global__ __launch_bounds__(256) void semihard_kernel(
    const float* __restrict__ G,
    const float* __restrict__ dg,
    const int* __restrict__ labels,
    unsigned long long* __restrict__ gsum,
    float* __restrict__ out)
{
  __shared__ float sd0[NPTS];
  __shared__ float sd1[NPTS];
  __shared__ int   slab[NPTS];
  __shared__ int   plist[256];
  __shared__ int   pcnt;
  __shared__ unsigned long long wsum[4], wcnt[4];

  const int a0 = blockIdx.x * 2;
  const int a1 = a0 + 1;
  const int t = threadIdx.x;
  const int wave = t >> 6;
  const int lane = t & 63;

  if (t == 0) pcnt = 0;

  {
    const float da0 = dg[a0];
    const float da1 = dg[a1];
    #pragma unroll
    for (int h = 0; h < 2; ++h) {
      const int idx = t + (h << 8);
      const float dt = dg[idx];
      const float g0 = G[a0 * NPTS + idx];
      const float g1 = G[a1 * NPTS + idx];
      slab[idx] = labels[idx];
      const float v0 = da0 + dt - 2.f * g0;
      const float v1 = da1 + dt - 2.f * g1;
      sd0[idx] = v0 > 0.f ? v0 : 0.f;
      sd1[idx] = v1 > 0.f ? v1 : 0.f;
    }
  }
  __syncthreads();

  {
    #pragma unroll
    for (int h = 0; h < 2; ++h) {
      const int idx = t + (h << 8);
      const int lp = slab[idx];
      if (idx != a0 && lp == slab[a0]) { int k = atomicAdd(&pcnt, 1); plist[k] = idx; }
      if (idx != a1 && lp == slab[a1]) { int k = atomicAdd(&pcnt, 1); plist[k] = (1 << 16) | idx; }
    }
  }
  __syncthreads();

  // Hoist this lane's 8 candidate slots into registers (reused across pairs).
  float d0v[8], d1v[8];
  int labv[8];
  #pragma unroll
  for (int k = 0; k < 8; ++k) {
    const int j = lane + (k << 6);
    d0v[k] = sd0[j];
    d1v[k] = sd1[j];
    labv[k] = slab[j];
  }

  unsigned long long lsum = 0ull, lcnt = 0ull;
  const int np = pcnt;
  for (int e = wave; e < np; e += 4) {
    const int ent = plist[e];
    const int ai = ent >> 16;
    const int p = ent & 0xffff;
    const int ag = ai ? a1 : a0;
    const int la = slab[ag];
    const float dap = ai ? sd1[p] : sd0[p];
    const float hi = dap + MARGIN_F;
    const uint32_t base = ((uint32_t)ag << 18) | ((uint32_t)p << 9);

    int bestKey = -1, bestJ = 0;
    #pragma unroll
    for (int k = 0; k < 8; ++k) {
      const int j = lane + (k << 6);
      const float dj = ai ? d1v[k] : d0v[k];
      if (labv[k] != la && dj > dap && dj < hi) {
        const int key = (int)(threefry_bits(base + (uint32_t)j) >> 9);
        if (key > bestKey) { bestKey = key; bestJ = j; }
      }
    }
    #pragma unroll
    for (int m = 32; m; m >>= 1) {
      const int ok = __shfl_xor(bestKey, m);
      const int oj = __shfl_xor(bestJ, m);
      if (ok > bestKey || (ok == bestKey && oj < bestJ)) { bestKey = ok; bestJ = oj; }
    }
    if (lane == 0 && bestKey >= 0) {
      const float term = (dap - (ai ? sd1[bestJ] : sd0[bestJ])) + MARGIN_F;
      lsum += (unsigned long long)((double)term * FIX_SCALE + 0.5);
      lcnt += 1ull;
    }
  }

  if (lane == 0) { wsum[wave] = lsum; wcnt[wave] = lcnt; }
  __syncthreads();
  if (t == 0) {
    unsigned long long s = 0ull, c = 0ull;
    #pragma unroll
    for (int w = 0; w < 4; ++w) { s += wsum[w]; c += wcnt[w]; }
    const unsigned long long contrib =
        (1ull << DONE_SHIFT) | (c << CNT_SHIFT) | s;
    const unsigned long long old = atomicAdd(gsum, contrib);
    if ((old >> DONE_SHIFT) == (unsigned long long)(NBLK - 1)) {
      const unsigned long long tot = old + contrib;
      const unsigned long long sum = tot & ((1ull << SUM_BITS) - 1ull);
      const unsigned long long cnt = (tot >> CNT_SHIFT) & 0x3FFFull;
      const double sd = (double)sum / FIX_SCALE;
      const double cd = cnt ? (double)cnt : 1.0;
      out[0] = (float)(sd / cd);
    }
  }
}

extern "C" void kernel_launch(void* const* d_in, const int* in_sizes, int n_in,
                              void* d_out, int out_size, void* d_ws, size_t ws_size,
                              hipStream_t stream) {
  const float* emb  = (const float*)d_in[0];
  const int* labels = (const int*)d_in[1];
  float* out        = (float*)d_out;

  char* ws = (char*)d_ws;
  unsigned long long* gsum = (unsigned long long*)ws;          // 8 B
  float* dg = (float*)(ws + 2048);                             // 512 * 4 B
  float* G  = (float*)(ws + 8192);                             // 1 MB

  gram_kernel<<<dim3(256), dim3(256), 0, stream>>>(emb, G, dg, gsum);
  semihard_kernel<<<dim3(NBLK), dim3(256), 0, stream>>>(G, dg, labels, gsum, out);
}

// Round 14
// 16.681 us; speedup vs baseline: 1.9703x; 1.1621x over previous
//
#include <hip/hip_runtime.h>
#include <cstdint>

#define NPTS 512
#define DIM 256
#define NBLK (NPTS / 2)
#define TK 32
#define NTILE 16
#define NTRI 136            // 16*17/2 upper-triangular tiles
#define LDB 264             // bf16 elements per LDS row (padded: 528 B/row)
#define MARGIN_F 0.2f
#define FIX_SCALE 1073741824.0   // 2^30
#define SUM_BITS 42
#define CNT_SHIFT 42
#define DONE_SHIFT 56

typedef __attribute__((ext_vector_type(8))) short bf16x8;   // 8 bf16 = 4 VGPR
typedef __attribute__((ext_vector_type(4))) float f32x4;

__device__ __forceinline__ uint32_t rotl32(uint32_t x, uint32_t r) {
  return (x << r) | (x >> (32u - r));
}

__device__ __forceinline__ ushort f2bf(float f) {   // RNE float->bf16
  uint32_t u = __float_as_uint(f);
  return (ushort)((u + 0x7FFFu + ((u >> 16) & 1u)) >> 16);
}
__device__ __forceinline__ float bf2f(ushort h) {
  return __uint_as_float(((uint32_t)h) << 16);
}

// Split 8 floats into packed hi/lo bf16 uint4s (RNE, lo = f - hi exactly).
__device__ __forceinline__ void split8(const float4 v0, const float4 v1,
                                       uint4& hi, uint4& lo) {
  const float f[8] = {v0.x, v0.y, v0.z, v0.w, v1.x, v1.y, v1.z, v1.w};
  uint32_t h[8], l[8];
  #pragma unroll
  for (int e = 0; e < 8; ++e) {
    const ushort hh = f2bf(f[e]);
    h[e] = hh;
    l[e] = f2bf(f[e] - bf2f(hh));
  }
  hi.x = h[0] | (h[1] << 16); hi.y = h[2] | (h[3] << 16);
  hi.z = h[4] | (h[5] << 16); hi.w = h[6] | (h[7] << 16);
  lo.x = l[0] | (l[1] << 16); lo.y = l[2] | (l[3] << 16);
  lo.z = l[4] | (l[5] << 16); lo.w = l[6] | (l[7] << 16);
}

// JAX threefry2x32, key (0, 42), partitionable mode: bits = out0 ^ out1,
// counter x = (hi32(m)=0, lo32(m)=m). Verified bit-exact (absmax 0.0, r1-r13).
__device__ __forceinline__ uint32_t threefry_bits(uint32_t c1) {
  const uint32_t k0 = 0u, k1 = 42u;
  const uint32_t k2 = k0 ^ k1 ^ 0x1BD11BDAu;
  uint32_t x0 = 0u + k0;
  uint32_t x1 = c1 + k1;
#define TFR(r) { x0 += x1; x1 = rotl32(x1, r); x1 ^= x0; }
  TFR(13u) TFR(15u) TFR(26u) TFR(6u)
  x0 += k1; x1 += k2 + 1u;
  TFR(17u) TFR(29u) TFR(16u) TFR(24u)
  x0 += k2; x1 += k0 + 2u;
  TFR(13u) TFR(15u) TFR(26u) TFR(6u)
  x0 += k0; x1 += k1 + 3u;
  TFR(17u) TFR(29u) TFR(16u) TFR(24u)
  x0 += k1; x1 += k2 + 4u;
  TFR(13u) TFR(15u) TFR(26u) TFR(6u)
  x0 += k2; x1 += k0 + 5u;
#undef TFR
  return x0 ^ x1;
}

// ---- K1: Gram via bf16-split MFMA, UPPER-TRIANGULAR grid (136 blocks). ----
// Block -> tile (ti,tj), ti<=tj; off-diagonal tiles mirror-write G[c][r]=G[r][c]
// (<=1 ulp vs natively computed transpose: only the hl/lh add order differs).
// Per-block work identical to r11; total waves 2048 -> 1088.
__global__ __launch_bounds__(512) void gram_kernel(
    const float* __restrict__ emb,
    float* __restrict__ G,
    float* __restrict__ dg,
    unsigned long long* __restrict__ gsum)
{
  __shared__ __align__(16) ushort Ahi[TK][LDB];
  __shared__ __align__(16) ushort Alo[TK][LDB];
  __shared__ __align__(16) ushort Bhi[TK][LDB];
  __shared__ __align__(16) ushort Blo[TK][LDB];

  const int b = blockIdx.x;
  // decode b -> (ti, tj), ti<=tj (wave-uniform scalar loop, <=16 iters)
  int bb = b, ti = 0, rowlen = NTILE;
  while (bb >= rowlen) { bb -= rowlen; --rowlen; ++ti; }
  const int tj = ti + bb;

  const int t = threadIdx.x;
  const int wave = t >> 6;
  const int lane = t & 63;

  if (b == 0 && t == 0) *gsum = 0ull;   // replaces a memset dispatch

  // ---- stage + split-convert: 1024 8-float chunks / 512 threads = 2 each --
  #pragma unroll
  for (int iter = 0; iter < 2; ++iter) {
    const int cidx = (iter << 9) + t;   // 0..1023
    const int r = cidx >> 5;            // row 0..31
    const int c8 = cidx & 31;           // 8-float chunk within row
    const float* pa = emb + (ti * TK + r) * DIM + c8 * 8;
    const float4 a0 = *reinterpret_cast<const float4*>(pa);
    const float4 a1 = *reinterpret_cast<const float4*>(pa + 4);
    uint4 ahi, alo;
    split8(a0, a1, ahi, alo);
    *reinterpret_cast<uint4*>(&Ahi[r][c8 * 8]) = ahi;
    *reinterpret_cast<uint4*>(&Alo[r][c8 * 8]) = alo;
    uint4 bhi, blo;
    if (ti == tj) { bhi = ahi; blo = alo; }
    else {
      const float* pb = emb + (tj * TK + r) * DIM + c8 * 8;
      const float4 b0 = *reinterpret_cast<const float4*>(pb);
      const float4 b1 = *reinterpret_cast<const float4*>(pb + 4);
      split8(b0, b1, bhi, blo);
    }
    *reinterpret_cast<uint4*>(&Bhi[r][c8 * 8]) = bhi;
    *reinterpret_cast<uint4*>(&Blo[r][c8 * 8]) = blo;
  }
  __syncthreads();

  // ---- MFMA phase: waves 0-3, quadrant (qr,qc) = (wave>>1, wave&1) ----
  if (wave < 4) {
    const int qr = wave >> 1, qc = wave & 1;
    const int frow = qr * 16 + (lane & 15);   // A-fragment row
    const int fcol = qc * 16 + (lane & 15);   // B-fragment col (B^T row)
    const int kg = lane >> 4;                 // k-group 0..3

    f32x4 acc_h  = {0.f, 0.f, 0.f, 0.f};
    f32x4 acc_hl = {0.f, 0.f, 0.f, 0.f};
    f32x4 acc_lh = {0.f, 0.f, 0.f, 0.f};
    #pragma unroll
    for (int s = 0; s < 8; ++s) {
      const int kb = s * 32 + kg * 8;
      const bf16x8 ah = *reinterpret_cast<const bf16x8*>(&Ahi[frow][kb]);
      const bf16x8 al = *reinterpret_cast<const bf16x8*>(&Alo[frow][kb]);
      const bf16x8 bh = *reinterpret_cast<const bf16x8*>(&Bhi[fcol][kb]);
      const bf16x8 bl = *reinterpret_cast<const bf16x8*>(&Blo[fcol][kb]);
      acc_h  = __builtin_amdgcn_mfma_f32_16x16x32_bf16(ah, bh, acc_h,  0, 0, 0);
      acc_hl = __builtin_amdgcn_mfma_f32_16x16x32_bf16(ah, bl, acc_hl, 0, 0, 0);
      acc_lh = __builtin_amdgcn_mfma_f32_16x16x32_bf16(al, bh, acc_lh, 0, 0, 0);
    }

    // C/D layout (m89): col = lane&15, row = (lane>>4)*4 + j
    const int lc = qc * 16 + (lane & 15);
    #pragma unroll
    for (int j = 0; j < 4; ++j) {
      const int lr = qr * 16 + (lane >> 4) * 4 + j;
      const float g = (acc_h[j] + acc_hl[j]) + acc_lh[j];
      const int gr = ti * TK + lr;
      const int gc = tj * TK + lc;
      G[gr * NPTS + gc] = g;
      if (ti != tj)       G[gc * NPTS + gr] = g;   // mirror (<=1 ulp)
      else if (lr == lc)  dg[gr] = g;
    }
  }
}

// ---- K2: semi-hard scan (verbatim r11). One block per 2 anchors. ----
__global__ __launch_bounds__(512) void semihard_kernel(
    const float* __restrict__ G,
    const float* __restrict__ dg,
    const int* __restrict__ labels,
    unsigned long long* __restrict__ gsum,
    float* __restrict__ out)
{
  __shared__ float sd0[NPTS];
  __shared__ float sd1[NPTS];
  __shared__ int   slab[NPTS];
  __shared__ int   plist[256];
  __shared__ int   pcnt;
  __shared__ unsigned long long wsum[8], wcnt[8];

  const int a0 = blockIdx.x * 2;
  const int a1 = a0 + 1;
  const int t = threadIdx.x;
  const int wave = t >> 6;
  const int lane = t & 63;

  if (t == 0) pcnt = 0;

  {
    const float da0 = dg[a0];
    const float da1 = dg[a1];
    const float dt  = dg[t];
    const float g0 = G[a0 * NPTS + t];
    const float g1 = G[a1 * NPTS + t];
    slab[t] = labels[t];
    const float v0 = da0 + dt - 2.f * g0;
    const float v1 = da1 + dt - 2.f * g1;
    sd0[t] = v0 > 0.f ? v0 : 0.f;
    sd1[t] = v1 > 0.f ? v1 : 0.f;
  }
  __syncthreads();

  {
    const int lp = slab[t];
    if (t != a0 && lp == slab[a0]) { int k = atomicAdd(&pcnt, 1); plist[k] = t; }
    if (t != a1 && lp == slab[a1]) { int k = atomicAdd(&pcnt, 1); plist[k] = (1 << 16) | t; }
  }
  __syncthreads();

  // Hoist this lane's 8 candidate slots into registers (reused across pairs).
  float d0v[8], d1v[8];
  int labv[8];
  #pragma unroll
  for (int k = 0; k < 8; ++k) {
    const int j = lane + (k << 6);
    d0v[k] = sd0[j];
    d1v[k] = sd1[j];
    labv[k] = slab[j];
  }

  unsigned long long lsum = 0ull, lcnt = 0ull;
  const int np = pcnt;
  for (int e = wave; e < np; e += 8) {
    const int ent = plist[e];
    const int ai = ent >> 16;
    const int p = ent & 0xffff;
    const int ag = ai ? a1 : a0;
    const int la = slab[ag];
    const float dap = ai ? sd1[p] : sd0[p];
    const float hi = dap + MARGIN_F;
    const uint32_t base = ((uint32_t)ag << 18) | ((uint32_t)p << 9);

    int bestKey = -1, bestJ = 0;
    #pragma unroll
    for (int k = 0; k < 8; ++k) {
      const int j = lane + (k << 6);
      const float dj = ai ? d1v[k] : d0v[k];
      if (labv[k] != la && dj > dap && dj < hi) {
        const int key = (int)(threefry_bits(base + (uint32_t)j) >> 9);
        if (key > bestKey) { bestKey = key; bestJ = j; }
      }
    }
    #pragma unroll
    for (int m = 32; m; m >>= 1) {
      const int ok = __shfl_xor(bestKey, m);
      const int oj = __shfl_xor(bestJ, m);
      if (ok > bestKey || (ok == bestKey && oj < bestJ)) { bestKey = ok; bestJ = oj; }
    }
    if (lane == 0 && bestKey >= 0) {
      const float term = (dap - (ai ? sd1[bestJ] : sd0[bestJ])) + MARGIN_F;
      lsum += (unsigned long long)((double)term * FIX_SCALE + 0.5);
      lcnt += 1ull;
    }
  }

  if (lane == 0) { wsum[wave] = lsum; wcnt[wave] = lcnt; }
  __syncthreads();
  if (t == 0) {
    unsigned long long s = 0ull, c = 0ull;
    #pragma unroll
    for (int w = 0; w < 8; ++w) { s += wsum[w]; c += wcnt[w]; }
    const unsigned long long contrib =
        (1ull << DONE_SHIFT) | (c << CNT_SHIFT) | s;
    const unsigned long long old = atomicAdd(gsum, contrib);
    if ((old >> DONE_SHIFT) == (unsigned long long)(NBLK - 1)) {
      const unsigned long long tot = old + contrib;
      const unsigned long long sum = tot & ((1ull << SUM_BITS) - 1ull);
      const unsigned long long cnt = (tot >> CNT_SHIFT) & 0x3FFFull;
      const double sd = (double)sum / FIX_SCALE;
      const double cd = cnt ? (double)cnt : 1.0;
      out[0] = (float)(sd / cd);
    }
  }
}

extern "C" void kernel_launch(void* const* d_in, const int* in_sizes, int n_in,
                              void* d_out, int out_size, void* d_ws, size_t ws_size,
                              hipStream_t stream) {
  const float* emb  = (const float*)d_in[0];
  const int* labels = (const int*)d_in[1];
  float* out        = (float*)d_out;

  char* ws = (char*)d_ws;
  unsigned long long* gsum = (unsigned long long*)ws;          // 8 B
  float* dg = (float*)(ws + 2048);                             // 512 * 4 B
  float* G  = (float*)(ws + 8192);                             // 1 MB

  gram_kernel<<<dim3(NTRI), dim3(512), 0, stream>>>(emb, G, dg, gsum);
  semihard_kernel<<<dim3(NBLK), dim3(512), 0, stream>>>(G, dg, labels, gsum, out);
}